// Round 5
// baseline (107.678 us; speedup 1.0000x reference)
//
#include <hip/hip_runtime.h>

#define Bsz 32
#define Nn  1024
#define Ff  128

typedef __attribute__((ext_vector_type(8))) short bf16x8;
typedef __attribute__((ext_vector_type(4))) float f32x4;

// round-to-nearest-even f32 -> bf16 (bit pattern as short)
static __device__ inline short f2bf(float f) {
    unsigned u = __builtin_bit_cast(unsigned, f);
    unsigned r = u + 0x7FFFu + ((u >> 16) & 1u);
    return (short)(r >> 16);
}
static __device__ inline unsigned pack2(float lo, float hi) {
    return (unsigned)(unsigned short)f2bf(lo) | ((unsigned)(unsigned short)f2bf(hi) << 16);
}

// ---------------------------------------------------------------------------
// k0: w f32 [k][g] -> wT bf16 [g][k]  (k-contiguous for MFMA fragments)
// ---------------------------------------------------------------------------
__global__ __launch_bounds__(256) void k0_wt(
    const float* __restrict__ w, short* __restrict__ wT)
{
    int gid = blockIdx.x * blockDim.x + threadIdx.x;
    if (gid < Ff * Ff) {
        int g = gid >> 7, k = gid & 127;
        wT[gid] = f2bf(w[k * Ff + g]);
    }
}

// ---------------------------------------------------------------------------
// k_mega: one block = one 128x128 y-tile of one batch.
// Phase 1: recompute vw for this block's 128 A-rows (swapped MFMA:
//   mfma(wT_rows, feats_rows) -> lane holds row i fixed, 4 consecutive g
//   -> packed ds_write_b64 into XOR-swizzled LDS tile [128][128] bf16).
// Phase 2: A-frags from LDS (ds_read_b128), B-frags converted on the fly
//   from f32 feats; blocks with nt==mt (wm==0) also store the f32 B-rows
//   to out_feats (free passthrough copy). Swapped MFMA again so the
//   epilogue is 1 global_store_dwordx4 per fragment (r3-verified layout).
// ---------------------------------------------------------------------------
__global__ __launch_bounds__(256, 4) void k_mega(
    const float* __restrict__ feats,
    const short* __restrict__ wT,
    const float* __restrict__ bias,
    float* __restrict__ y,
    float* __restrict__ out_feats)
{
    __shared__ unsigned char vw_lds[128 * 256];   // 32 KB: [row][g] bf16, swizzled

    const int blk  = blockIdx.x;
    const int bidx = blk >> 6;
    const int t    = blk & 63;
    const int mt = t >> 3, nt = t & 7;

    const int tid  = threadIdx.x;
    const int wid  = tid >> 6;
    const int lane = tid & 63;
    const int lr = lane & 15;
    const int kg = lane >> 4;
    const int swz = (lr & 7) << 4;    // row&7 == lr&7 for all rows we touch

    const float* F = feats + (size_t)bidx * Nn * Ff;

    // ---------------- phase 1: vw tile (this block's 128 rows) ----------------
    {
        f32x4 acc1[2][8] = {};
        const int ar0 = mt * 128 + wid * 32;      // wave owns 32 rows
        for (int kc = 0; kc < 4; ++kc) {
            const int k0 = kc * 32 + kg * 8;
            bf16x8 af[2];
            for (int ic = 0; ic < 2; ++ic) {
                const float* p = F + (size_t)(ar0 + ic * 16 + lr) * Ff + k0;
                float4 v0 = ((const float4*)p)[0];
                float4 v1 = ((const float4*)p)[1];
                af[ic] = (bf16x8){ f2bf(v0.x), f2bf(v0.y), f2bf(v0.z), f2bf(v0.w),
                                   f2bf(v1.x), f2bf(v1.y), f2bf(v1.z), f2bf(v1.w) };
            }
            for (int gc = 0; gc < 8; ++gc) {
                bf16x8 wf = *((const bf16x8*)(wT + (size_t)(gc * 16 + lr) * Ff + k0));
                for (int ic = 0; ic < 2; ++ic)
                    acc1[ic][gc] = __builtin_amdgcn_mfma_f32_16x16x32_bf16(
                        wf, af[ic], acc1[ic][gc], 0, 0, 0);
            }
        }
        // D layout: lane holds i = ichunk*16+lr (fixed), g = gc*16 + kg*4 + r
        for (int ic = 0; ic < 2; ++ic) {
            const int i = wid * 32 + ic * 16 + lr;   // block-local row
            for (int gc = 0; gc < 8; ++gc) {
                uint2 u;
                u.x = pack2(acc1[ic][gc][0], acc1[ic][gc][1]);
                u.y = pack2(acc1[ic][gc][2], acc1[ic][gc][3]);
                *((uint2*)&vw_lds[i * 256 + ((gc * 32 + kg * 8) ^ swz)]) = u;
            }
        }
    }
    __syncthreads();

    // ---------------- phase 2: y tile ----------------
    const int wm = wid >> 1, wn = wid & 1;
    f32x4 acc[4][4] = {};    // [nf][mf], transposed-tile accumulators

    const float* Brow0 = F + (size_t)(nt * 128 + wn * 64) * Ff;
    const bool dumpB = (nt == mt) && (wm == 0);
    float* OF = out_feats + ((size_t)bidx * Nn + nt * 128 + wn * 64) * Ff;

    for (int kc = 0; kc < 4; ++kc) {
        const int k0 = kc * 32 + kg * 8;
        bf16x8 af[4];
        for (int mf = 0; mf < 4; ++mf) {
            const int row = wm * 64 + mf * 16 + lr;
            af[mf] = *((const bf16x8*)&vw_lds[row * 256 + ((kc * 64 + kg * 16) ^ swz)]);
        }
        for (int nf = 0; nf < 4; ++nf) {
            const float* bp = Brow0 + (size_t)(nf * 16 + lr) * Ff + k0;
            float4 b0 = ((const float4*)bp)[0];
            float4 b1 = ((const float4*)bp)[1];
            if (dumpB) {
                float* op = OF + (size_t)(nf * 16 + lr) * Ff + k0;
                ((float4*)op)[0] = b0;
                ((float4*)op)[1] = b1;
            }
            bf16x8 bf = (bf16x8){ f2bf(b0.x), f2bf(b0.y), f2bf(b0.z), f2bf(b0.w),
                                  f2bf(b1.x), f2bf(b1.y), f2bf(b1.z), f2bf(b1.w) };
            for (int mf = 0; mf < 4; ++mf)
                acc[nf][mf] = __builtin_amdgcn_mfma_f32_16x16x32_bf16(
                    bf, af[mf], acc[nf][mf], 0, 0, 0);
        }
    }

    // epilogue: lane's y-row = mt*128 + wm*64 + mf*16 + lr,
    //           y-cols = nt*128 + wn*64 + nf*16 + kg*4 .. +3
    const float bv = bias[0];
    float* Y = y + (size_t)bidx * Nn * Nn;
    for (int mf = 0; mf < 4; ++mf) {
        float* rowp = Y + (size_t)(mt * 128 + wm * 64 + mf * 16 + lr) * Nn
                        + nt * 128 + wn * 64 + kg * 4;
        for (int nf = 0; nf < 4; ++nf) {
            f32x4 v;
            v[0] = acc[nf][mf][0] + bv;
            v[1] = acc[nf][mf][1] + bv;
            v[2] = acc[nf][mf][2] + bv;
            v[3] = acc[nf][mf][3] + bv;
            *((f32x4*)(rowp + nf * 16)) = v;
        }
    }
}

extern "C" void kernel_launch(void* const* d_in, const int* in_sizes, int n_in,
                              void* d_out, int out_size, void* d_ws, size_t ws_size,
                              hipStream_t stream) {
    const float* feats = (const float*)d_in[1];
    const float* w     = (const float*)d_in[2];
    const float* bias  = (const float*)d_in[3];
    float* y = (float*)d_out;
    float* out_feats = y + (size_t)Bsz * Nn * Nn;

    short* wT = (short*)d_ws;

    k0_wt<<<64, 256, 0, stream>>>(w, wT);
    k_mega<<<2048, 256, 0, stream>>>(feats, wT, bias, y, out_feats);
}

// Round 6
// 73.978 us; speedup vs baseline: 1.4555x; 1.4555x over previous
//
#include <hip/hip_runtime.h>

#define Bsz 32
#define Nn  1024
#define Ff  128

typedef __attribute__((ext_vector_type(8))) short bf16x8;
typedef __attribute__((ext_vector_type(4))) float f32x4;
typedef __attribute__((ext_vector_type(4))) short s16x4;

// round-to-nearest-even f32 -> bf16 (bit pattern as short)
static __device__ inline short f2bf(float f) {
    unsigned u = __builtin_bit_cast(unsigned, f);
    unsigned r = u + 0x7FFFu + ((u >> 16) & 1u);
    return (short)(r >> 16);
}
static __device__ inline unsigned pack2(float lo, float hi) {
    return (unsigned)(unsigned short)f2bf(lo) | ((unsigned)(unsigned short)f2bf(hi) << 16);
}

// ---------------------------------------------------------------------------
// prep: feats f32 -> passthrough copy (d_out tail) + bf16 copy (ws);
//       w f32 [k][g] -> wT bf16 [g][k]. Identical to round-1 prep.
// ---------------------------------------------------------------------------
__global__ __launch_bounds__(256) void prep_kernel(
    const float* __restrict__ feats,
    const float* __restrict__ w,
    float* __restrict__ out_feats,
    short* __restrict__ feats_bf,
    short* __restrict__ wT_bf)
{
    int gid = blockIdx.x * blockDim.x + threadIdx.x;
    const int total4 = Bsz * Nn * Ff / 4;
    if (gid < total4) {
        float4 v = ((const float4*)feats)[gid];
        ((float4*)out_feats)[gid] = v;
        s16x4 s;
        s.x = f2bf(v.x); s.y = f2bf(v.y); s.z = f2bf(v.z); s.w = f2bf(v.w);
        ((s16x4*)feats_bf)[gid] = s;
    }
    if (gid < Ff * Ff) {
        int g = gid >> 7, k = gid & 127;
        wT_bf[gid] = f2bf(w[k * Ff + g]);
    }
}

// ---------------------------------------------------------------------------
// gemm1: vw = feats @ w, bf16 out. SWAPPED operands: mfma(wT_frag, feats_frag)
// -> D layout puts lane on ONE row (col=lane&15=lr) and 4 consecutive g
// (row=(lane>>4)*4+reg) -> packed uint2 (4xbf16, 8B) stores, 32B segments.
// Block = 32 rows x 128 g, 4 waves (2 row-halves x 2 g-halves);
// wave = 16 rows x 64 g. Grid 1024 blocks = 16 waves/CU.
// ---------------------------------------------------------------------------
__global__ __launch_bounds__(256) void gemm1_kernel(
    const float* __restrict__ feats,   // [B*N, F] f32
    const short* __restrict__ wT,      // [F, F] bf16, g-major
    short* __restrict__ vw)            // [B*N, F] bf16
{
    const int row0 = blockIdx.x * 32;
    const int tid  = threadIdx.x;
    const int wid  = tid >> 6;
    const int lane = tid & 63;
    const int wr = wid >> 1, wg = wid & 1;
    const int lr = lane & 15;
    const int kg = lane >> 4;

    const int myrow = row0 + wr * 16 + lr;
    const float* frow = feats + (size_t)myrow * Ff;

    f32x4 acc[4] = {};

    for (int kc = 0; kc < 4; ++kc) {
        const int k0 = kc * 32 + kg * 8;
        float4 v0 = ((const float4*)(frow + k0))[0];
        float4 v1 = ((const float4*)(frow + k0))[1];
        bf16x8 a = (bf16x8){ f2bf(v0.x), f2bf(v0.y), f2bf(v0.z), f2bf(v0.w),
                             f2bf(v1.x), f2bf(v1.y), f2bf(v1.z), f2bf(v1.w) };
        for (int gc = 0; gc < 4; ++gc) {
            bf16x8 wf = *((const bf16x8*)(wT + (size_t)(wg * 64 + gc * 16 + lr) * Ff + k0));
            acc[gc] = __builtin_amdgcn_mfma_f32_16x16x32_bf16(wf, a, acc[gc], 0, 0, 0);
        }
    }

    // lane's row = myrow (fixed); g = wg*64 + gc*16 + kg*4 + r, r=0..3
    short* vrow = vw + (size_t)myrow * Ff + wg * 64 + kg * 4;
    for (int gc = 0; gc < 4; ++gc) {
        uint2 u;
        u.x = pack2(acc[gc][0], acc[gc][1]);
        u.y = pack2(acc[gc][2], acc[gc][3]);
        *((uint2*)(vrow + gc * 16)) = u;
    }
}

// ---------------------------------------------------------------------------
// gemm2: y[b][i][j] = sum_g vw[b][i][g] * fb[b][j][g] + bias
// Round-1 main loop (natural block order, NO XCD swizzle) + round-3's
// swapped-operand epilogue: acc[nf][mf] = mfma(b[nf], a[mf], acc) puts each
// lane's 4 acc regs at one y-row, four consecutive y-cols
// -> 1 global_store_dwordx4 per fragment. No LDS, no barriers.
// ---------------------------------------------------------------------------
__global__ __launch_bounds__(256) void gemm2_kernel(
    const short* __restrict__ vw,     // [B, N, F] bf16
    const short* __restrict__ fb,     // [B, N, F] bf16
    const float* __restrict__ bias,
    float* __restrict__ y)            // [B, N, N]
{
    int blk  = blockIdx.x;
    int bidx = blk >> 6;
    int t    = blk & 63;
    int mt = t >> 3, nt = t & 7;

    int tid = threadIdx.x;
    int wid = tid >> 6, lane = tid & 63;
    int wm = wid >> 1, wn = wid & 1;
    int lr = lane & 15, kg = lane >> 4;

    const short* A  = vw + (size_t)bidx * Nn * Ff;
    const short* Bp = fb + (size_t)bidx * Nn * Ff;
    int am0 = mt * 128 + wm * 64;
    int bn0 = nt * 128 + wn * 64;

    f32x4 acc[4][4] = {};   // [nf][mf] — transposed-tile accumulators

    for (int kc = 0; kc < 4; ++kc) {
        int k0 = kc * 32 + kg * 8;
        bf16x8 a[4], b[4];
        for (int mf = 0; mf < 4; ++mf)
            a[mf] = *((const bf16x8*)(A + (size_t)(am0 + mf * 16 + lr) * Ff + k0));
        for (int nf = 0; nf < 4; ++nf)
            b[nf] = *((const bf16x8*)(Bp + (size_t)(bn0 + nf * 16 + lr) * Ff + k0));
        for (int nf = 0; nf < 4; ++nf)
            for (int mf = 0; mf < 4; ++mf)
                acc[nf][mf] = __builtin_amdgcn_mfma_f32_16x16x32_bf16(
                    b[nf], a[mf], acc[nf][mf], 0, 0, 0);
    }

    float bv = bias[0];
    float* Y = y + (size_t)bidx * Nn * Nn;

    // lane's y-row for mf: am0 + mf*16 + lr; y-cols for nf: bn0 + nf*16 + kg*4..+3
    for (int mf = 0; mf < 4; ++mf) {
        float* rowp = Y + (size_t)(am0 + mf * 16 + lr) * Nn + bn0 + kg * 4;
        for (int nf = 0; nf < 4; ++nf) {
            f32x4 v;
            v[0] = acc[nf][mf][0] + bv;
            v[1] = acc[nf][mf][1] + bv;
            v[2] = acc[nf][mf][2] + bv;
            v[3] = acc[nf][mf][3] + bv;
            *((f32x4*)(rowp + nf * 16)) = v;
        }
    }
}

extern "C" void kernel_launch(void* const* d_in, const int* in_sizes, int n_in,
                              void* d_out, int out_size, void* d_ws, size_t ws_size,
                              hipStream_t stream) {
    const float* feats = (const float*)d_in[1];
    const float* w     = (const float*)d_in[2];
    const float* bias  = (const float*)d_in[3];
    float* y = (float*)d_out;
    float* out_feats = y + (size_t)Bsz * Nn * Nn;

    short* vw = (short*)d_ws;
    short* fb = vw + (size_t)Bsz * Nn * Ff;
    short* wT = fb + (size_t)Bsz * Nn * Ff;

    prep_kernel<<<4096, 256, 0, stream>>>(feats, w, out_feats, fb, wT);
    gemm1_kernel<<<1024, 256, 0, stream>>>(feats, wT, vw);
    gemm2_kernel<<<2048, 256, 0, stream>>>(vw, fb, bias, y);
}

// Round 7
// 65.439 us; speedup vs baseline: 1.6455x; 1.1305x over previous
//
#include <hip/hip_runtime.h>

#define Bsz 32
#define Nn  1024
#define Ff  128

typedef __attribute__((ext_vector_type(8))) short bf16x8;
typedef __attribute__((ext_vector_type(4))) float f32x4;

// round-to-nearest-even f32 -> bf16 (bit pattern as short)
static __device__ inline short f2bf(float f) {
    unsigned u = __builtin_bit_cast(unsigned, f);
    unsigned r = u + 0x7FFFu + ((u >> 16) & 1u);
    return (short)(r >> 16);
}

// ---------------------------------------------------------------------------
// k0: w f32 [k][g] -> wT bf16 [g][k]  (verbatim r3)
// ---------------------------------------------------------------------------
__global__ __launch_bounds__(256) void k0_wt(
    const float* __restrict__ w, short* __restrict__ wT)
{
    int gid = blockIdx.x * blockDim.x + threadIdx.x;
    if (gid < Ff * Ff) {
        int g = gid >> 7, k = gid & 127;
        wT[gid] = f2bf(w[k * Ff + g]);
    }
}

// ---------------------------------------------------------------------------
// k1_fused (verbatim r3, refcheck'd): per 64-row block, wave owns 16 rows.
// Single feats read feeds: f32 passthrough copy, bf16 fb copy, and the
// MFMA A-fragment for vw = feats @ w. wT fragments L1-resident.
// ---------------------------------------------------------------------------
__global__ __launch_bounds__(256) void k1_fused(
    const float* __restrict__ feats,
    const short* __restrict__ wT,
    float* __restrict__ out_feats,
    short* __restrict__ fb,
    short* __restrict__ vw)
{
    const int row0 = blockIdx.x * 64;
    const int tid  = threadIdx.x;
    const int wid  = tid >> 6;
    const int lane = tid & 63;
    const int lr = lane & 15;
    const int kg = lane >> 4;

    const int myrow = row0 + wid * 16 + lr;
    const float* frow = feats + (size_t)myrow * Ff;
    float* orow       = out_feats + (size_t)myrow * Ff;
    short* brow       = fb + (size_t)myrow * Ff;

    f32x4 acc[8] = {};

    for (int kc = 0; kc < 4; ++kc) {
        int k0 = kc * 32 + kg * 8;
        float4 v0 = ((const float4*)(frow + k0))[0];
        float4 v1 = ((const float4*)(frow + k0))[1];
        ((float4*)(orow + k0))[0] = v0;
        ((float4*)(orow + k0))[1] = v1;
        bf16x8 a = (bf16x8){ f2bf(v0.x), f2bf(v0.y), f2bf(v0.z), f2bf(v0.w),
                             f2bf(v1.x), f2bf(v1.y), f2bf(v1.z), f2bf(v1.w) };
        *((bf16x8*)(brow + k0)) = a;
        for (int nf = 0; nf < 8; ++nf) {
            bf16x8 b = *((const bf16x8*)(wT + (size_t)(nf * 16 + lr) * Ff + k0));
            acc[nf] = __builtin_amdgcn_mfma_f32_16x16x32_bf16(a, b, acc[nf], 0, 0, 0);
        }
    }

    // C/D layout: col = lane&15, row = (lane>>4)*4 + reg
    for (int nf = 0; nf < 8; ++nf) {
        int g = nf * 16 + lr;
        for (int r = 0; r < 4; ++r)
            vw[(size_t)(row0 + wid * 16 + kg * 4 + r) * Ff + g] = f2bf(acc[nf][r]);
    }
}

// ---------------------------------------------------------------------------
// gemm2: y[b][i][j] = sum_g vw[b][i][g] * fb[b][j][g] + bias
// Main loop + epilogue VERBATIM from round 1 (the 65.8 µs baseline:
// unswapped mfma(a,b), acc[mf][nf], scalar-store epilogue).
// ONLY the block-index decode changed: super-tile mapping. Each XCD
// (assumed blk%8 round-robin) gets 512x512 y-regions: the 16 blocks of a
// super-tile all have the same blk%8, so one XCD's L2 holds that region's
// A+B panels (256 KB) -> panels fetched ~2x from HBM instead of 8x.
// ---------------------------------------------------------------------------
__global__ __launch_bounds__(256) void gemm2_kernel(
    const short* __restrict__ vw,     // [B, N, F] bf16
    const short* __restrict__ fb,     // [B, N, F] bf16
    const float* __restrict__ bias,
    float* __restrict__ y)            // [B, N, N]
{
    // super-tile decode: blk -> (xcd, chunk, k) -> (bidx, super, inner tile)
    int blk   = blockIdx.x;
    int xcd   = blk & 7;
    int q     = blk >> 3;         // 0..255
    int chunk = q >> 4;           // 0..15
    int k     = q & 15;           // 0..15 within super-tile
    int super_id = chunk * 8 + xcd;   // 0..127, bijective
    int bidx  = super_id >> 2;        // 0..31
    int s     = super_id & 3;
    int sm = s >> 1, sn = s & 1;      // 2x2 supers of 512x512
    int mt = sm * 4 + (k >> 2);
    int nt = sn * 4 + (k & 3);

    int tid = threadIdx.x;
    int wid = tid >> 6, lane = tid & 63;
    int wm = wid >> 1, wn = wid & 1;
    int lr = lane & 15, kg = lane >> 4;

    const short* A  = vw + (size_t)bidx * Nn * Ff;
    const short* Bp = fb + (size_t)bidx * Nn * Ff;
    int am0 = mt * 128 + wm * 64;
    int bn0 = nt * 128 + wn * 64;

    f32x4 acc[4][4] = {};

    for (int kc = 0; kc < 4; ++kc) {
        int k0 = kc * 32 + kg * 8;
        bf16x8 a[4], b[4];
        for (int mf = 0; mf < 4; ++mf)
            a[mf] = *((const bf16x8*)(A + (size_t)(am0 + mf * 16 + lr) * Ff + k0));
        for (int nf = 0; nf < 4; ++nf)
            b[nf] = *((const bf16x8*)(Bp + (size_t)(bn0 + nf * 16 + lr) * Ff + k0));
        for (int mf = 0; mf < 4; ++mf)
            for (int nf = 0; nf < 4; ++nf)
                acc[mf][nf] = __builtin_amdgcn_mfma_f32_16x16x32_bf16(
                    a[mf], b[nf], acc[mf][nf], 0, 0, 0);
    }

    float bv = bias[0];
    float* Y = y + (size_t)bidx * Nn * Nn;
    for (int mf = 0; mf < 4; ++mf) {
        int row = am0 + mf * 16 + kg * 4;
        for (int nf = 0; nf < 4; ++nf) {
            int col = bn0 + nf * 16 + lr;
            float* p = Y + (size_t)row * Nn + col;
            for (int r = 0; r < 4; ++r)
                p[(size_t)r * Nn] = acc[mf][nf][r] + bv;
        }
    }
}

extern "C" void kernel_launch(void* const* d_in, const int* in_sizes, int n_in,
                              void* d_out, int out_size, void* d_ws, size_t ws_size,
                              hipStream_t stream) {
    const float* feats = (const float*)d_in[1];
    const float* w     = (const float*)d_in[2];
    const float* bias  = (const float*)d_in[3];
    float* y = (float*)d_out;
    float* out_feats = y + (size_t)Bsz * Nn * Nn;

    short* vw = (short*)d_ws;
    short* fb = vw + (size_t)Bsz * Nn * Ff;
    short* wT = fb + (size_t)Bsz * Nn * Ff;

    k0_wt<<<64, 256, 0, stream>>>(w, wT);
    k1_fused<<<512, 256, 0, stream>>>(feats, wT, out_feats, fb, vw);
    gemm2_kernel<<<2048, 256, 0, stream>>>(vw, fb, bias, y);
}